// Round 3
// baseline (572.717 us; speedup 1.0000x reference)
//
#include <hip/hip_runtime.h>
#include <hip/hip_bf16.h>

#define BATCH 16384
#define HDIM  1024
#define K1    2048
#define N1    4096

typedef __attribute__((ext_vector_type(4))) float f32x4;
typedef __attribute__((ext_vector_type(8))) short short8;

__device__ __forceinline__ unsigned short f2bf(float f) {
  union { float f; unsigned u; } v; v.f = f;
  unsigned r = v.u + 0x7FFFu + ((v.u >> 16) & 1u);
  return (unsigned short)(r >> 16);
}
__device__ __forceinline__ float bf2f(unsigned short h) {
  union { unsigned u; float f; } v; v.u = ((unsigned)h) << 16; return v.f;
}
__device__ __forceinline__ float sigmoidf_(float x) {
  return 1.0f / (1.0f + __builtin_amdgcn_exp2f(x * -1.4426950408889634f));
}
__device__ __forceinline__ float tanhf_(float x) {
  float xc = fminf(fmaxf(x, -8.0f), 8.0f);
  float e = __builtin_amdgcn_exp2f(xc * 2.8853900817779268f);
  return (e - 1.0f) / (e + 1.0f);
}
__device__ __forceinline__ void async16(const void* g, void* l) {
  __builtin_amdgcn_global_load_lds((const __attribute__((address_space(1))) void*)g,
                                   (__attribute__((address_space(3))) void*)l, 16, 0, 0);
}

// ---- conversion pass: U = [x|y] bf16 (16384 x 2048) ----
__global__ void k_convU(const float* __restrict__ x, const float* __restrict__ y,
                        unsigned short* __restrict__ U) {
  const int total = BATCH * (HDIM / 4);
  for (int q = blockIdx.x * blockDim.x + threadIdx.x; q < total;
       q += gridDim.x * blockDim.x) {
    int b = q >> 8;
    int c = (q & 255) << 2;
    float4 xv = *(const float4*)(x + (long)b * HDIM + c);
    float4 yv = *(const float4*)(y + (long)b * HDIM + c);
    uint2 xo, yo;
    xo.x = (unsigned)f2bf(xv.x) | ((unsigned)f2bf(xv.y) << 16);
    xo.y = (unsigned)f2bf(xv.z) | ((unsigned)f2bf(xv.w) << 16);
    yo.x = (unsigned)f2bf(yv.x) | ((unsigned)f2bf(yv.y) << 16);
    yo.y = (unsigned)f2bf(yv.z) | ((unsigned)f2bf(yv.w) << 16);
    *(uint2*)(U + (long)b * K1 + c) = xo;
    *(uint2*)(U + (long)b * K1 + HDIM + c) = yo;
  }
}

// ---- conversion pass: permuted Wcat (4096 x 2048) + Wz bf16 ----
// n' = B*256 + w*64 + c*16 + i  maps to chunk c of h = B*64 + w*16 + i
// c0: [W_ih[h]     | W_hh[h]     ]   (i_dt1 + h_dt1)
// c1: [W_ih[H+h]   | W_hh[H+h]   ]   (i_dt2 + h_dt2)
// c2: [W_ih[3H+h]  | W_hh[2H+h]  ]   (i_y   + h_y  )
// c3: [W_ih[2H+h]  | 0           ]   (i_z)
__global__ void k_convW(const float* __restrict__ Wih, const float* __restrict__ Whh,
                        const float* __restrict__ Wz,
                        unsigned short* __restrict__ Wcat, unsigned short* __restrict__ Wzb) {
  const int stride = gridDim.x * blockDim.x;
  const int totalW = N1 * (K1 / 4);
  for (int q = blockIdx.x * blockDim.x + threadIdx.x; q < totalW; q += stride) {
    int np = q >> 9;
    int kb = (q & 511) << 2;
    int B = np >> 8, w = (np >> 6) & 3, c = (np >> 4) & 3, i = np & 15;
    int h = B * 64 + w * 16 + i;
    float4 v;
    if (kb < HDIM) {
      int row = (c == 0) ? h : (c == 1) ? (HDIM + h) : (c == 2) ? (3 * HDIM + h) : (2 * HDIM + h);
      v = *(const float4*)(Wih + (long)row * HDIM + kb);
    } else if (c == 3) {
      v = make_float4(0.f, 0.f, 0.f, 0.f);
    } else {
      int row = (c == 0) ? h : (c == 1) ? (HDIM + h) : (2 * HDIM + h);
      v = *(const float4*)(Whh + (long)row * HDIM + (kb - HDIM));
    }
    uint2 o;
    o.x = (unsigned)f2bf(v.x) | ((unsigned)f2bf(v.y) << 16);
    o.y = (unsigned)f2bf(v.z) | ((unsigned)f2bf(v.w) << 16);
    *(uint2*)(Wcat + (long)np * K1 + kb) = o;
  }
  const int totalZ = HDIM * (HDIM / 4);
  for (int q = blockIdx.x * blockDim.x + threadIdx.x; q < totalZ; q += stride) {
    int n = q >> 8;
    int kb = (q & 255) << 2;
    float4 v = *(const float4*)(Wz + (long)n * HDIM + kb);
    uint2 o;
    o.x = (unsigned)f2bf(v.x) | ((unsigned)f2bf(v.y) << 16);
    o.y = (unsigned)f2bf(v.z) | ((unsigned)f2bf(v.w) << 16);
    *(uint2*)(Wzb + (long)n * HDIM + kb) = o;
  }
}

// ---- 256x256 deep-pipelined GEMM core ----
// BK=32, 4 LDS tile-buffers (2-tile staging lead), 8 waves (2M x 4N),
// 2 phases/tile x 16 MFMA, counted vmcnt(4), setprio around MFMA.
// LDS XOR-swizzle: physical col slot = logical ^ ((row>>1)&3)<<4, so the
// 16B-slot index (addr bits [6:4]) = (rA&1)<<2 | (rA>>1)&3 = rA&7 -> all 8
// slots covered uniformly within every 8-lane group (bank-conflict floor).
// Staged via inverse-swizzled GLOBAL source + linear global_load_lds dest.
template <int KTOT>
__device__ __forceinline__ void gemm256(const unsigned short* __restrict__ A,
                                        const unsigned short* __restrict__ B,
                                        long arow0, long brow0,
                                        char* AsBase, char* BsBase,
                                        f32x4 acc[8][4]) {
  const int t = threadIdx.x;
  const int lane = t & 63;
  const int wv = t >> 6;
  const int wm = wv >> 2, wn = wv & 3;
  const int rA = lane & 15;
  const int cphys = (((lane >> 4) << 4)) ^ (((rA >> 1) & 3) << 4);
  const int t16 = t * 16;
  const int s0 = t16 ^ (((t >> 3) & 3) << 4);   // inverse-swizzled source offset
  const int r0 = s0 >> 6, c0 = s0 & 63;
  const unsigned short* gA = A + (arow0 + r0) * (long)KTOT + (c0 >> 1);
  const unsigned short* gB = B + (brow0 + r0) * (long)KTOT + (c0 >> 1);
  const int NT = KTOT / 32;

  // prologue: stage tiles 0 and 1 (8 loads/wave), keep tile1 in flight
#pragma unroll
  for (int tt = 0; tt < 2; ++tt)
#pragma unroll
    for (int hh = 0; hh < 2; ++hh) {
      async16(gA + tt * 32 + (long)hh * 128 * KTOT, AsBase + tt * 16384 + hh * 8192 + t16);
      async16(gB + tt * 32 + (long)hh * 128 * KTOT, BsBase + tt * 16384 + hh * 8192 + t16);
    }
  asm volatile("s_waitcnt vmcnt(4)" ::: "memory");
  __builtin_amdgcn_s_barrier();

#pragma unroll 1
  for (int kt = 0; kt < NT; ++kt) {
    const char* Ab = AsBase + (kt & 3) * 16384;
    const char* Bb = BsBase + (kt & 3) * 16384;
    short8 bfr[4];
#pragma unroll
    for (int ph = 0; ph < 2; ++ph) {
      short8 af[4];
#pragma unroll
      for (int m = 0; m < 4; ++m) {
        const int R = wm * 128 + ph * 64 + m * 16 + rA;
        af[m] = *(const short8*)(Ab + R * 64 + cphys);
      }
      if (ph == 0) {
#pragma unroll
        for (int n = 0; n < 4; ++n) {
          const int R = wn * 64 + n * 16 + rA;
          bfr[n] = *(const short8*)(Bb + R * 64 + cphys);
        }
      }
      if (kt + 2 < NT) {  // stage half (ph) of tile kt+2 into its own buffer
        const int b2 = (kt + 2) & 3;
        const long ko = (long)(kt + 2) * 32 + (long)ph * 128 * KTOT;
        async16(gA + ko, AsBase + b2 * 16384 + ph * 8192 + t16);
        async16(gB + ko, BsBase + b2 * 16384 + ph * 8192 + t16);
      }
      __builtin_amdgcn_s_barrier();
      __builtin_amdgcn_s_setprio(1);
#pragma unroll
      for (int m = 0; m < 4; ++m)
#pragma unroll
        for (int n = 0; n < 4; ++n)
          acc[ph * 4 + m][n] = __builtin_amdgcn_mfma_f32_16x16x32_bf16(
              af[m], bfr[n], acc[ph * 4 + m][n], 0, 0, 0);
      __builtin_amdgcn_s_setprio(0);
      if (ph == 1) {
        if (kt < NT - 2)       asm volatile("s_waitcnt vmcnt(4)" ::: "memory");
        else if (kt == NT - 2) asm volatile("s_waitcnt vmcnt(0)" ::: "memory");
      }
      __builtin_amdgcn_s_barrier();
    }
  }
}

// ---- phase 1: fused U@Wcat^T + LEM elementwise ----
__global__ __launch_bounds__(512, 2) void k_gemm1(
    const unsigned short* __restrict__ U, const unsigned short* __restrict__ Wcat,
    const float* __restrict__ z, const float* __restrict__ dtp,
    const float* __restrict__ bih, const float* __restrict__ bhh,
    const float* __restrict__ Wdt, const float* __restrict__ bdt,
    float* __restrict__ out, unsigned short* __restrict__ znb,
    unsigned short* __restrict__ sbb) {
  __shared__ char As[65536];
  __shared__ char Bs[65536];
  const int bid = blockIdx.x;
  const int sid = (bid & 7) * 128 + (bid >> 3);  // XCD-bijective swizzle (1024 % 8 == 0)
  const int bm = sid >> 4, bn = sid & 15;
  f32x4 acc[8][4];
#pragma unroll
  for (int r = 0; r < 8; ++r)
#pragma unroll
    for (int n = 0; n < 4; ++n) acc[r][n] = (f32x4)(0.0f);

  gemm256<K1>(U, Wcat, (long)bm * 256, (long)bn * 256, As, Bs, acc);

  const int t = threadIdx.x, lane = t & 63, wv = t >> 6;
  const int wm = wv >> 2, wn = wv & 3;
  const int rA = lane & 15, q4 = (lane >> 4) << 2;
  const int h = bn * 64 + wn * 16 + rA;
  const int rowbase = bm * 256 + wm * 128;
  const float bi0 = bih[h] + bhh[h];
  const float bi1 = bih[HDIM + h] + bhh[HDIM + h];
  const float bi2 = bih[3 * HDIM + h] + bhh[2 * HDIM + h];
  const float bi3 = bih[2 * HDIM + h];
  const float wdt0 = Wdt[0], wdt1 = Wdt[1], bdt0 = bdt[0], bdt1 = bdt[1];
#pragma unroll
  for (int r = 0; r < 8; ++r) {
    const int rowblk = (r >> 2) * 64 + (r & 3) * 16;
#pragma unroll
    for (int j = 0; j < 4; ++j) {
      const int b = rowbase + rowblk + q4 + j;
      const long idx = (long)b * HDIM + h;
      const float dv = dtp[b];
      const float s1 = sigmoidf_(dv * wdt0 + bdt0);
      const float s2 = sigmoidf_(dv * wdt1 + bdt1);
      const float sbar = s1 * sigmoidf_(acc[r][0][j] + bi0);
      const float s = s2 * sigmoidf_(acc[r][1][j] + bi1);
      const float zt = tanhf_(acc[r][2][j] + bi2);
      const float iz = acc[r][3][j] + bi3;
      const float znew = (1.0f - s) * z[idx] + s * zt;
      out[(long)BATCH * HDIM + idx] = znew;  // z_new output (f32)
      out[idx] = iz;                          // park i_z in y_new slot
      znb[idx] = f2bf(znew);                  // bf16 operand for phase 2
      sbb[idx] = f2bf(sbar);
    }
  }
}

// ---- phase 2: z_new@Wz^T + y_new epilogue ----
__global__ __launch_bounds__(512, 2) void k_gemm2(
    const unsigned short* __restrict__ Zn, const unsigned short* __restrict__ Wzb,
    const unsigned short* __restrict__ sbb, const float* __restrict__ yin,
    const float* __restrict__ bz, float* __restrict__ out) {
  __shared__ char As[65536];
  __shared__ char Bs[65536];
  const int bid = blockIdx.x;
  const int sid = (bid & 7) * 32 + (bid >> 3);  // 256 % 8 == 0
  const int bm = sid >> 2, bn = sid & 3;
  f32x4 acc[8][4];
#pragma unroll
  for (int r = 0; r < 8; ++r)
#pragma unroll
    for (int n = 0; n < 4; ++n) acc[r][n] = (f32x4)(0.0f);

  gemm256<HDIM>(Zn, Wzb, (long)bm * 256, (long)bn * 256, As, Bs, acc);

  const int t = threadIdx.x, lane = t & 63, wv = t >> 6;
  const int wm = wv >> 2, wn = wv & 3;
  const int rA = lane & 15, q4 = (lane >> 4) << 2;
  const int rowbase = bm * 256 + wm * 128;
#pragma unroll
  for (int n = 0; n < 4; ++n) {
    const int hc = bn * 256 + wn * 64 + n * 16 + rA;
    const float bzv = bz[hc];
#pragma unroll
    for (int r = 0; r < 8; ++r) {
      const int rowblk = (r >> 2) * 64 + (r & 3) * 16;
#pragma unroll
      for (int j = 0; j < 4; ++j) {
        const int b = rowbase + rowblk + q4 + j;
        const long idx = (long)b * HDIM + hc;
        const float tv = tanhf_(acc[r][n][j] + bzv + out[idx]);  // out[idx] holds i_z
        const float sb = bf2f(sbb[idx]);
        out[idx] = (1.0f - sb) * yin[idx] + sb * tv;  // y_new (same addr, same thread)
      }
    }
  }
}

extern "C" void kernel_launch(void* const* d_in, const int* in_sizes, int n_in,
                              void* d_out, int out_size, void* d_ws, size_t ws_size,
                              hipStream_t stream) {
  const float* x   = (const float*)d_in[0];
  const float* y   = (const float*)d_in[1];
  const float* z   = (const float*)d_in[2];
  const float* dtp = (const float*)d_in[3];
  const float* Wih = (const float*)d_in[4];
  const float* bih = (const float*)d_in[5];
  const float* Whh = (const float*)d_in[6];
  const float* bhh = (const float*)d_in[7];
  const float* Wz  = (const float*)d_in[8];
  const float* bz  = (const float*)d_in[9];
  const float* Wdt = (const float*)d_in[10];
  const float* bdt = (const float*)d_in[11];

  char* ws = (char*)d_ws;
  unsigned short* U    = (unsigned short*)(ws);              // 67,108,864 B
  unsigned short* Wcat = (unsigned short*)(ws + 67108864);   // 16,777,216 B
  unsigned short* Wzb  = (unsigned short*)(ws + 83886080);   //  2,097,152 B
  unsigned short* Znb  = (unsigned short*)(ws + 85983232);   // 33,554,432 B
  unsigned short* Sbb  = (unsigned short*)(ws + 119537664);  // 33,554,432 B -> total 153,092,096 B
  float* out = (float*)d_out;

  k_convU<<<2048, 256, 0, stream>>>(x, y, U);
  k_convW<<<2048, 256, 0, stream>>>(Wih, Whh, Wz, Wcat, Wzb);
  k_gemm1<<<1024, 512, 0, stream>>>(U, Wcat, z, dtp, bih, bhh, Wdt, bdt, out, Znb, Sbb);
  k_gemm2<<<256, 512, 0, stream>>>(Znb, Wzb, Sbb, y, bz, out);
}

// Round 4
// 526.923 us; speedup vs baseline: 1.0869x; 1.0869x over previous
//
#include <hip/hip_runtime.h>
#include <hip/hip_bf16.h>

#define BATCH 16384
#define HDIM  1024
#define K1    2048
#define N1    4096

typedef __attribute__((ext_vector_type(4))) float f32x4;
typedef __attribute__((ext_vector_type(8))) short short8;

__device__ __forceinline__ unsigned short f2bf(float f) {
  union { float f; unsigned u; } v; v.f = f;
  unsigned r = v.u + 0x7FFFu + ((v.u >> 16) & 1u);
  return (unsigned short)(r >> 16);
}
__device__ __forceinline__ float bf2f(unsigned short h) {
  union { unsigned u; float f; } v; v.u = ((unsigned)h) << 16; return v.f;
}
__device__ __forceinline__ float sigmoidf_(float x) {
  return 1.0f / (1.0f + __builtin_amdgcn_exp2f(x * -1.4426950408889634f));
}
__device__ __forceinline__ float tanhf_(float x) {
  float xc = fminf(fmaxf(x, -8.0f), 8.0f);
  float e = __builtin_amdgcn_exp2f(xc * 2.8853900817779268f);
  return (e - 1.0f) / (e + 1.0f);
}
__device__ __forceinline__ void async16(const void* g, void* l) {
  __builtin_amdgcn_global_load_lds((const __attribute__((address_space(1))) void*)g,
                                   (__attribute__((address_space(3))) void*)l, 16, 0, 0);
}

// ---- conversion pass: U = [x|y] bf16 (16384 x 2048) ----
__global__ void k_convU(const float* __restrict__ x, const float* __restrict__ y,
                        unsigned short* __restrict__ U) {
  const int total = BATCH * (HDIM / 4);
  for (int q = blockIdx.x * blockDim.x + threadIdx.x; q < total;
       q += gridDim.x * blockDim.x) {
    int b = q >> 8;
    int c = (q & 255) << 2;
    float4 xv = *(const float4*)(x + (long)b * HDIM + c);
    float4 yv = *(const float4*)(y + (long)b * HDIM + c);
    uint2 xo, yo;
    xo.x = (unsigned)f2bf(xv.x) | ((unsigned)f2bf(xv.y) << 16);
    xo.y = (unsigned)f2bf(xv.z) | ((unsigned)f2bf(xv.w) << 16);
    yo.x = (unsigned)f2bf(yv.x) | ((unsigned)f2bf(yv.y) << 16);
    yo.y = (unsigned)f2bf(yv.z) | ((unsigned)f2bf(yv.w) << 16);
    *(uint2*)(U + (long)b * K1 + c) = xo;
    *(uint2*)(U + (long)b * K1 + HDIM + c) = yo;
  }
}

// ---- conversion pass: permuted Wcat (4096 x 2048) + Wz bf16 ----
// n' = B*256 + w*64 + c*16 + i  maps to chunk c of h = B*64 + w*16 + i
// c0: [W_ih[h]     | W_hh[h]     ]   (i_dt1 + h_dt1)
// c1: [W_ih[H+h]   | W_hh[H+h]   ]   (i_dt2 + h_dt2)
// c2: [W_ih[3H+h]  | W_hh[2H+h]  ]   (i_y   + h_y  )
// c3: [W_ih[2H+h]  | 0           ]   (i_z)
__global__ void k_convW(const float* __restrict__ Wih, const float* __restrict__ Whh,
                        const float* __restrict__ Wz,
                        unsigned short* __restrict__ Wcat, unsigned short* __restrict__ Wzb) {
  const int stride = gridDim.x * blockDim.x;
  const int totalW = N1 * (K1 / 4);
  for (int q = blockIdx.x * blockDim.x + threadIdx.x; q < totalW; q += stride) {
    int np = q >> 9;
    int kb = (q & 511) << 2;
    int B = np >> 8, w = (np >> 6) & 3, c = (np >> 4) & 3, i = np & 15;
    int h = B * 64 + w * 16 + i;
    float4 v;
    if (kb < HDIM) {
      int row = (c == 0) ? h : (c == 1) ? (HDIM + h) : (c == 2) ? (3 * HDIM + h) : (2 * HDIM + h);
      v = *(const float4*)(Wih + (long)row * HDIM + kb);
    } else if (c == 3) {
      v = make_float4(0.f, 0.f, 0.f, 0.f);
    } else {
      int row = (c == 0) ? h : (c == 1) ? (HDIM + h) : (2 * HDIM + h);
      v = *(const float4*)(Whh + (long)row * HDIM + (kb - HDIM));
    }
    uint2 o;
    o.x = (unsigned)f2bf(v.x) | ((unsigned)f2bf(v.y) << 16);
    o.y = (unsigned)f2bf(v.z) | ((unsigned)f2bf(v.w) << 16);
    *(uint2*)(Wcat + (long)np * K1 + kb) = o;
  }
  const int totalZ = HDIM * (HDIM / 4);
  for (int q = blockIdx.x * blockDim.x + threadIdx.x; q < totalZ; q += stride) {
    int n = q >> 8;
    int kb = (q & 255) << 2;
    float4 v = *(const float4*)(Wz + (long)n * HDIM + kb);
    uint2 o;
    o.x = (unsigned)f2bf(v.x) | ((unsigned)f2bf(v.y) << 16);
    o.y = (unsigned)f2bf(v.z) | ((unsigned)f2bf(v.w) << 16);
    *(uint2*)(Wzb + (long)n * HDIM + kb) = o;
  }
}

// ---- 256x256 deep-pipelined GEMM core, single-barrier slip schedule ----
// BK=32, 4 LDS tile-buffers, staging distance 3, 8 waves (2M x 4N).
// Per kt: {12 ds_read (full kt fragments); 4 global_load_lds (tile kt+3);
//          s_waitcnt vmcnt(8) lgkmcnt(0); s_barrier; 32 MFMA}.
// ONE barrier per kt -> fast waves slip into next kt's LDS/stage work while
// slow waves still MFMA (cross-wave LDS||MFMA overlap). Hazards:
//  - lgkmcnt(0) BEFORE barrier: all reads of a buffer complete before any
//    wave can pass the barrier and later overwrite it (distance-3 staging).
//  - counted vmcnt(8) (4/0 at tail) before barrier: tile kt+1 staged by all.
// LDS XOR-swizzle (slot = rA&7) via pre-swizzled global source, 0 conflicts.
template <int KTOT>
__device__ __forceinline__ void gemm256(const unsigned short* __restrict__ A,
                                        const unsigned short* __restrict__ B,
                                        long arow0, long brow0,
                                        char* AsBase, char* BsBase,
                                        f32x4 acc[8][4]) {
  const int t = threadIdx.x;
  const int lane = t & 63;
  const int wv = t >> 6;
  const int wm = wv >> 2, wn = wv & 3;
  const int rA = lane & 15;
  const int cphys = (((lane >> 4) << 4)) ^ (((rA >> 1) & 3) << 4);
  const int t16 = t * 16;
  const int s0 = t16 ^ (((t >> 3) & 3) << 4);   // inverse-swizzled source offset
  const int r0 = s0 >> 6, c0 = s0 & 63;
  const unsigned short* gA = A + (arow0 + r0) * (long)KTOT + (c0 >> 1);
  const unsigned short* gB = B + (brow0 + r0) * (long)KTOT + (c0 >> 1);
  const int NT = KTOT / 32;

  // prologue: stage tiles 0,1,2 (12 loads/thread)
#pragma unroll
  for (int tt = 0; tt < 3; ++tt)
#pragma unroll
    for (int hh = 0; hh < 2; ++hh) {
      async16(gA + tt * 32 + (long)hh * 128 * KTOT, AsBase + tt * 16384 + hh * 8192 + t16);
      async16(gB + tt * 32 + (long)hh * 128 * KTOT, BsBase + tt * 16384 + hh * 8192 + t16);
    }
  asm volatile("s_waitcnt vmcnt(8)" ::: "memory");
  __builtin_amdgcn_s_barrier();

#pragma unroll 1
  for (int kt = 0; kt < NT; ++kt) {
    const char* Ab = AsBase + (kt & 3) * 16384;
    const char* Bb = BsBase + (kt & 3) * 16384;
    short8 af[8], bfr[4];
#pragma unroll
    for (int m = 0; m < 8; ++m) {
      const int R = wm * 128 + (m >> 2) * 64 + (m & 3) * 16 + rA;
      af[m] = *(const short8*)(Ab + R * 64 + cphys);
    }
#pragma unroll
    for (int n = 0; n < 4; ++n) {
      const int R = wn * 64 + n * 16 + rA;
      bfr[n] = *(const short8*)(Bb + R * 64 + cphys);
    }
    if (kt + 3 < NT) {  // stage tile kt+3 into buffer (kt+3)&3 = (kt-1)&3
      const int b3 = (kt + 3) & 3;
      const long ko = (long)(kt + 3) * 32;
#pragma unroll
      for (int hh = 0; hh < 2; ++hh) {
        async16(gA + ko + (long)hh * 128 * KTOT, AsBase + b3 * 16384 + hh * 8192 + t16);
        async16(gB + ko + (long)hh * 128 * KTOT, BsBase + b3 * 16384 + hh * 8192 + t16);
      }
    }
    if (kt + 3 < NT)      asm volatile("s_waitcnt vmcnt(8) lgkmcnt(0)" ::: "memory");
    else if (kt + 2 < NT) asm volatile("s_waitcnt vmcnt(4) lgkmcnt(0)" ::: "memory");
    else                  asm volatile("s_waitcnt vmcnt(0) lgkmcnt(0)" ::: "memory");
    __builtin_amdgcn_s_barrier();
    __builtin_amdgcn_sched_barrier(0);
    __builtin_amdgcn_s_setprio(1);
#pragma unroll
    for (int m = 0; m < 8; ++m)
#pragma unroll
      for (int n = 0; n < 4; ++n)
        acc[m][n] = __builtin_amdgcn_mfma_f32_16x16x32_bf16(af[m], bfr[n], acc[m][n], 0, 0, 0);
    __builtin_amdgcn_s_setprio(0);
  }
}

// ---- phase 1: fused U@Wcat^T + LEM elementwise ----
__global__ __launch_bounds__(512, 2) void k_gemm1(
    const unsigned short* __restrict__ U, const unsigned short* __restrict__ Wcat,
    const float* __restrict__ z, const float* __restrict__ dtp,
    const float* __restrict__ bih, const float* __restrict__ bhh,
    const float* __restrict__ Wdt, const float* __restrict__ bdt,
    float* __restrict__ out, unsigned short* __restrict__ znb,
    unsigned short* __restrict__ sbb) {
  __shared__ char As[65536];
  __shared__ char Bs[65536];
  const int bid = blockIdx.x;
  const int sid = (bid & 7) * 128 + (bid >> 3);  // XCD-bijective swizzle (1024 % 8 == 0)
  const int bm = sid >> 4, bn = sid & 15;
  f32x4 acc[8][4];
#pragma unroll
  for (int r = 0; r < 8; ++r)
#pragma unroll
    for (int n = 0; n < 4; ++n) acc[r][n] = (f32x4)(0.0f);

  gemm256<K1>(U, Wcat, (long)bm * 256, (long)bn * 256, As, Bs, acc);

  const int t = threadIdx.x, lane = t & 63, wv = t >> 6;
  const int wm = wv >> 2, wn = wv & 3;
  const int rA = lane & 15, q4 = (lane >> 4) << 2;
  const int h = bn * 64 + wn * 16 + rA;
  const int rowbase = bm * 256 + wm * 128;
  const float bi0 = bih[h] + bhh[h];
  const float bi1 = bih[HDIM + h] + bhh[HDIM + h];
  const float bi2 = bih[3 * HDIM + h] + bhh[2 * HDIM + h];
  const float bi3 = bih[2 * HDIM + h];
  const float wdt0 = Wdt[0], wdt1 = Wdt[1], bdt0 = bdt[0], bdt1 = bdt[1];
#pragma unroll
  for (int r = 0; r < 8; ++r) {
    const int rowblk = (r >> 2) * 64 + (r & 3) * 16;
#pragma unroll
    for (int j = 0; j < 4; ++j) {
      const int b = rowbase + rowblk + q4 + j;
      const long idx = (long)b * HDIM + h;
      const float dv = dtp[b];
      const float s1 = sigmoidf_(dv * wdt0 + bdt0);
      const float s2 = sigmoidf_(dv * wdt1 + bdt1);
      const float sbar = s1 * sigmoidf_(acc[r][0][j] + bi0);
      const float s = s2 * sigmoidf_(acc[r][1][j] + bi1);
      const float zt = tanhf_(acc[r][2][j] + bi2);
      const float iz = acc[r][3][j] + bi3;
      const float znew = (1.0f - s) * z[idx] + s * zt;
      out[(long)BATCH * HDIM + idx] = znew;  // z_new output (f32)
      out[idx] = iz;                          // park i_z in y_new slot
      znb[idx] = f2bf(znew);                  // bf16 operand for phase 2
      sbb[idx] = f2bf(sbar);
    }
  }
}

// ---- phase 2: z_new@Wz^T + y_new epilogue ----
__global__ __launch_bounds__(512, 2) void k_gemm2(
    const unsigned short* __restrict__ Zn, const unsigned short* __restrict__ Wzb,
    const unsigned short* __restrict__ sbb, const float* __restrict__ yin,
    const float* __restrict__ bz, float* __restrict__ out) {
  __shared__ char As[65536];
  __shared__ char Bs[65536];
  const int bid = blockIdx.x;
  const int sid = (bid & 7) * 32 + (bid >> 3);  // 256 % 8 == 0
  const int bm = sid >> 2, bn = sid & 3;
  f32x4 acc[8][4];
#pragma unroll
  for (int r = 0; r < 8; ++r)
#pragma unroll
    for (int n = 0; n < 4; ++n) acc[r][n] = (f32x4)(0.0f);

  gemm256<HDIM>(Zn, Wzb, (long)bm * 256, (long)bn * 256, As, Bs, acc);

  const int t = threadIdx.x, lane = t & 63, wv = t >> 6;
  const int wm = wv >> 2, wn = wv & 3;
  const int rA = lane & 15, q4 = (lane >> 4) << 2;
  const int rowbase = bm * 256 + wm * 128;
#pragma unroll
  for (int n = 0; n < 4; ++n) {
    const int hc = bn * 256 + wn * 64 + n * 16 + rA;
    const float bzv = bz[hc];
#pragma unroll
    for (int r = 0; r < 8; ++r) {
      const int rowblk = (r >> 2) * 64 + (r & 3) * 16;
#pragma unroll
      for (int j = 0; j < 4; ++j) {
        const int b = rowbase + rowblk + q4 + j;
        const long idx = (long)b * HDIM + hc;
        const float tv = tanhf_(acc[r][n][j] + bzv + out[idx]);  // out[idx] holds i_z
        const float sb = bf2f(sbb[idx]);
        out[idx] = (1.0f - sb) * yin[idx] + sb * tv;  // y_new (same addr, same thread)
      }
    }
  }
}

extern "C" void kernel_launch(void* const* d_in, const int* in_sizes, int n_in,
                              void* d_out, int out_size, void* d_ws, size_t ws_size,
                              hipStream_t stream) {
  const float* x   = (const float*)d_in[0];
  const float* y   = (const float*)d_in[1];
  const float* z   = (const float*)d_in[2];
  const float* dtp = (const float*)d_in[3];
  const float* Wih = (const float*)d_in[4];
  const float* bih = (const float*)d_in[5];
  const float* Whh = (const float*)d_in[6];
  const float* bhh = (const float*)d_in[7];
  const float* Wz  = (const float*)d_in[8];
  const float* bz  = (const float*)d_in[9];
  const float* Wdt = (const float*)d_in[10];
  const float* bdt = (const float*)d_in[11];

  char* ws = (char*)d_ws;
  unsigned short* U    = (unsigned short*)(ws);              // 67,108,864 B
  unsigned short* Wcat = (unsigned short*)(ws + 67108864);   // 16,777,216 B
  unsigned short* Wzb  = (unsigned short*)(ws + 83886080);   //  2,097,152 B
  unsigned short* Znb  = (unsigned short*)(ws + 85983232);   // 33,554,432 B
  unsigned short* Sbb  = (unsigned short*)(ws + 119537664);  // 33,554,432 B -> total 153,092,096 B
  float* out = (float*)d_out;

  k_convU<<<2048, 256, 0, stream>>>(x, y, U);
  k_convW<<<2048, 256, 0, stream>>>(Wih, Whh, Wz, Wcat, Wzb);
  k_gemm1<<<1024, 512, 0, stream>>>(U, Wcat, z, dtp, bih, bhh, Wdt, bdt, out, Znb, Sbb);
  k_gemm2<<<256, 512, 0, stream>>>(Znb, Wzb, Sbb, y, bz, out);
}